// Round 1
// baseline (566.971 us; speedup 1.0000x reference)
//
#include <hip/hip_runtime.h>
#include <hip/hip_bf16.h>

typedef __attribute__((ext_vector_type(8))) short short8;
typedef __attribute__((ext_vector_type(4))) short short4v;
typedef __attribute__((ext_vector_type(4))) float f32x4;

// ---------- helpers ----------
__device__ __forceinline__ short f2bf(float f) {
    union { float f; unsigned u; } v; v.f = f;
    unsigned r = v.u + 0x7FFF + ((v.u >> 16) & 1);   // RNE
    return (short)(r >> 16);
}

__device__ __forceinline__ void gll16(const short* g, short* l) {
    __builtin_amdgcn_global_load_lds(
        (const __attribute__((address_space(1))) void*)g,
        (__attribute__((address_space(3))) void*)l, 16, 0, 0);
}

// sizes
#define NE 4
#define CC 384
#define CO 1152
#define TT 8
#define NN 197
#define NB 32
#define BT 256
#define MOEW_ELEMS 5308416   // 4*1152*384*3
#define W_ELEMS    442368    // 1152*384

// ---------------------------------------------------------------
// P0: prep — rf, Y (cls windows, bf16), convert moe_w & weight to bf16
// blocks 0..31: per-b cls work; blocks 32..511: grid-stride convert
// ---------------------------------------------------------------
__global__ __launch_bounds__(256) void prep_kernel(
    const float* __restrict__ x, const float* __restrict__ rf_w,
    const float* __restrict__ rf_b, const float* __restrict__ moe_w,
    const float* __restrict__ weight,
    short* __restrict__ moeWb, short* __restrict__ Wb,
    short* __restrict__ Yb, float* __restrict__ rf)
{
    int blk = blockIdx.x, tid = threadIdx.x;
    if (blk < NB) {
        __shared__ float clsL[TT * CC];    // [t][c]
        __shared__ float pooled[CC];
        int b = blk;
        for (int flat = tid; flat < TT * CC; flat += 256) {
            int t = flat / CC, c = flat - t * CC;
            clsL[flat] = x[(size_t)(b * TT + t) * NN * CC + c];  // n = 0 (cls token)
        }
        __syncthreads();
        for (int c = tid; c < CC; c += 256) {
            float s = 0.f;
            #pragma unroll
            for (int t = 0; t < TT; t++) s += clsL[t * CC + c];
            pooled[c] = s * 0.125f;
        }
        // Y rows: Yb[(b*8+t)][c*3+k] = clsp[b][c][t+k-1]
        for (int t = 0; t < TT; t++)
            for (int flat = tid; flat < CC * 3; flat += 256) {
                int c = flat / 3, k = flat - c * 3;
                int u = t + k - 1;
                float v = (u >= 0 && u < TT) ? clsL[u * CC + c] : 0.f;
                Yb[(size_t)(b * TT + t) * (CC * 3) + flat] = f2bf(v);
            }
        __syncthreads();
        // rf[b][e]: wave e of 4 does a 64-lane dot-reduce
        int wave = tid >> 6, lane = tid & 63;
        float p = 0.f;
        for (int c = lane; c < CC; c += 64) p += pooled[c] * rf_w[wave * CC + c];
        #pragma unroll
        for (int off = 32; off; off >>= 1) p += __shfl_down(p, off, 64);
        if (lane == 0) rf[b * NE + wave] = p + rf_b[wave];
    } else {
        const long NU = (MOEW_ELEMS + W_ELEMS) / 4;   // float4 units
        long step = (long)(gridDim.x - NB) * 256;
        for (long unit = (long)(blk - NB) * 256 + tid; unit < NU; unit += step) {
            long idx = unit * 4;
            float4 v; short* dst;
            if (idx < MOEW_ELEMS) { v = *(const float4*)(moe_w + idx); dst = moeWb + idx; }
            else { long j = idx - MOEW_ELEMS; v = *(const float4*)(weight + j); dst = Wb + j; }
            short4v s;
            s.x = f2bf(v.x); s.y = f2bf(v.y); s.z = f2bf(v.z); s.w = f2bf(v.w);
            *(short4v*)dst = s;
        }
    }
}

// ---------------------------------------------------------------
// P1: P[4608][256] = moeWb[4608][1152] @ Yb[256][1152]^T   (bf16 MFMA)
// BM=64, BN=64, BK=64, grid (72,4)
// ---------------------------------------------------------------
__global__ __launch_bounds__(256) void gemm_P(
    const short* __restrict__ A, const short* __restrict__ B, float* __restrict__ P)
{
    __shared__ short A_lds[64 * 64];
    __shared__ short B_lds[64 * 64];
    int bm = blockIdx.x, bn = blockIdx.y, tid = threadIdx.x;
    int wave = tid >> 6, lane = tid & 63, l15 = lane & 15, lq = lane >> 4;
    f32x4 acc[4];
    #pragma unroll
    for (int j = 0; j < 4; j++) acc[j] = (f32x4){0.f, 0.f, 0.f, 0.f};

    for (int kk = 0; kk < 1152 / 64; kk++) {
        __syncthreads();
        #pragma unroll
        for (int j2 = 0; j2 < 2; j2++) {
            int flat = j2 * 256 + tid;          // 512 x 16B = 8KB each
            int row = flat >> 3, seg = flat & 7;
            gll16(A + (size_t)(bm * 64 + row) * 1152 + kk * 64 + seg * 8, &A_lds[flat * 8]);
            gll16(B + (size_t)(bn * 64 + row) * 1152 + kk * 64 + seg * 8, &B_lds[flat * 8]);
        }
        __syncthreads();
        #pragma unroll
        for (int ks = 0; ks < 2; ks++) {
            short8 a = *(short8*)&A_lds[(wave * 16 + l15) * 64 + ks * 32 + lq * 8];
            #pragma unroll
            for (int j = 0; j < 4; j++) {
                short8 bfr = *(short8*)&B_lds[(j * 16 + l15) * 64 + ks * 32 + lq * 8];
                acc[j] = __builtin_amdgcn_mfma_f32_16x16x32_bf16(a, bfr, acc[j], 0, 0, 0);
            }
        }
    }
    #pragma unroll
    for (int j = 0; j < 4; j++)
        #pragma unroll
        for (int reg = 0; reg < 4; reg++) {
            int row = bm * 64 + wave * 16 + lq * 4 + reg;   // eo
            int col = bn * 64 + j * 16 + l15;               // bt
            P[(size_t)row * 256 + col] = acc[j][reg];
        }
}

// ---------------------------------------------------------------
// P2: r_ws[bt][o] = 1 + sum_e rf[b][e]*(P[e*1152+o][bt] + moe_b[e][o])
// grid 1152 (o), 256 threads (bt)
// ---------------------------------------------------------------
__global__ __launch_bounds__(256) void combine_kernel(
    const float* __restrict__ P, const float* __restrict__ rf,
    const float* __restrict__ moe_b, float* __restrict__ r_ws)
{
    __shared__ float rf_l[NB * NE];
    int o = blockIdx.x, tid = threadIdx.x;
    if (tid < NB * NE) rf_l[tid] = rf[tid];
    __syncthreads();
    int b = tid >> 3;
    float acc = 1.0f;
    #pragma unroll
    for (int e = 0; e < NE; e++)
        acc += rf_l[b * NE + e] * (P[(size_t)(e * CO + o) * 256 + tid] + moe_b[e * CO + o]);
    r_ws[(size_t)tid * CO + o] = acc;
}

// ---------------------------------------------------------------
// Main: out[bt][o][n] = sum_c W[o][c]*r[bt][br*384+c]*x[bt][n][c] + bias[o]*r[bt][o]
// per-bt GEMM M=1152 N=197 K=384. BM=128 BN=112 BK=32.
// grid 4608 XCD-swizzled: all 9 M-tiles of a (bt,ntile) on one XCD.
// ---------------------------------------------------------------
__global__ __launch_bounds__(256) void main_gemm(
    const float* __restrict__ x, const short* __restrict__ Wb,
    const float* __restrict__ r_ws, const float* __restrict__ bias,
    float* __restrict__ out)
{
    __shared__ short A_lds[128 * 32];
    __shared__ short B_lds[112 * 32];
    __shared__ float r_l[CC];

    int g = blockIdx.x;
    int u = g & 7, w2 = g >> 3;
    int mt = w2 % 9;
    int pq = u + 8 * (w2 / 9);    // [0,512)
    int bt = pq >> 1, nt = pq & 1;
    int tid = threadIdx.x;
    int br = mt / 3;

    for (int i = tid; i < CC; i += 256) r_l[i] = r_ws[(size_t)bt * CO + br * CC + i];

    const short* Abase = Wb + (size_t)(mt * 128) * CC;
    const float* Xbase = x + (size_t)(bt * NN + nt * 112) * CC;

    f32x4 acc[2][7];
    #pragma unroll
    for (int i = 0; i < 2; i++)
        #pragma unroll
        for (int j = 0; j < 7; j++) acc[i][j] = (f32x4){0.f, 0.f, 0.f, 0.f};

    int wave = tid >> 6, lane = tid & 63, l15 = lane & 15, lq = lane >> 4;

    for (int kk = 0; kk < CC / 32; kk++) {
        __syncthreads();
        // A: 128x32 bf16 = 8KB via global_load_lds (512 16B chunks)
        #pragma unroll
        for (int j2 = 0; j2 < 2; j2++) {
            int flat = j2 * 256 + tid;
            int row = flat >> 2, seg = flat & 3;
            gll16(Abase + (size_t)row * CC + kk * 32 + seg * 8, &A_lds[flat * 8]);
        }
        // B: 112x32, load x fp32, scale by r, cvt bf16
        #pragma unroll
        for (int j2 = 0; j2 < 4; j2++) {
            int uix = j2 * 256 + tid;
            if (uix < 896) {
                int n = uix >> 3, seg = uix & 7;
                int c = kk * 32 + seg * 4;
                float4 v = {0.f, 0.f, 0.f, 0.f};
                if (nt * 112 + n < NN) v = *(const float4*)(Xbase + (size_t)n * CC + c);
                short4v s;
                s.x = f2bf(v.x * r_l[c + 0]);
                s.y = f2bf(v.y * r_l[c + 1]);
                s.z = f2bf(v.z * r_l[c + 2]);
                s.w = f2bf(v.w * r_l[c + 3]);
                *(short4v*)&B_lds[uix * 4] = s;
            }
        }
        __syncthreads();
        short8 a0 = *(short8*)&A_lds[(wave * 32 + l15) * 32 + lq * 8];
        short8 a1 = *(short8*)&A_lds[(wave * 32 + 16 + l15) * 32 + lq * 8];
        #pragma unroll
        for (int j = 0; j < 7; j++) {
            short8 bfr = *(short8*)&B_lds[(j * 16 + l15) * 32 + lq * 8];
            acc[0][j] = __builtin_amdgcn_mfma_f32_16x16x32_bf16(a0, bfr, acc[0][j], 0, 0, 0);
            acc[1][j] = __builtin_amdgcn_mfma_f32_16x16x32_bf16(a1, bfr, acc[1][j], 0, 0, 0);
        }
    }

    size_t outbase = (size_t)bt * (CO * NN);
    #pragma unroll
    for (int mi = 0; mi < 2; mi++)
        #pragma unroll
        for (int reg = 0; reg < 4; reg++) {
            int o = mt * 128 + wave * 32 + mi * 16 + lq * 4 + reg;
            float bo = bias[o] * r_ws[(size_t)bt * CO + o];
            #pragma unroll
            for (int j = 0; j < 7; j++) {
                int n = nt * 112 + j * 16 + l15;
                if (n < NN) out[outbase + (size_t)o * NN + n] = acc[mi][j][reg] + bo;
            }
        }
}

// ---------------------------------------------------------------
extern "C" void kernel_launch(void* const* d_in, const int* in_sizes, int n_in,
                              void* d_out, int out_size, void* d_ws, size_t ws_size,
                              hipStream_t stream) {
    const float* x      = (const float*)d_in[0];
    const float* rf_w   = (const float*)d_in[1];
    const float* rf_b   = (const float*)d_in[2];
    const float* moe_w  = (const float*)d_in[3];
    const float* moe_b  = (const float*)d_in[4];
    const float* weight = (const float*)d_in[5];
    const float* bias   = (const float*)d_in[6];
    float* out = (float*)d_out;

    char* ws = (char*)d_ws;
    short* Wb    = (short*)(ws + 0);            // 884,736 B
    short* moeWb = (short*)(ws + 884736);       // 10,616,832 B
    short* Yb    = (short*)(ws + 11501568);     // 589,824 B
    float* rf    = (float*)(ws + 12091392);     // 512 B
    float* P     = (float*)(ws + 12091904);     // 4,718,592 B
    float* r_ws  = (float*)(ws + 16810496);     // 1,179,648 B -> total ~18 MB

    prep_kernel<<<512, 256, 0, stream>>>(x, rf_w, rf_b, moe_w, weight, moeWb, Wb, Yb, rf);
    gemm_P<<<dim3(72, 4), 256, 0, stream>>>(moeWb, Yb, P);
    combine_kernel<<<1152, 256, 0, stream>>>(P, rf, moe_b, r_ws);
    main_gemm<<<4608, 256, 0, stream>>>(x, Wb, r_ws, bias, out);
}

// Round 2
// 460.412 us; speedup vs baseline: 1.2314x; 1.2314x over previous
//
#include <hip/hip_runtime.h>
#include <hip/hip_bf16.h>

typedef __attribute__((ext_vector_type(8))) short short8;
typedef __attribute__((ext_vector_type(4))) short short4v;
typedef __attribute__((ext_vector_type(4))) float f32x4;

// ---------- helpers ----------
__device__ __forceinline__ short f2bf(float f) {
    union { float f; unsigned u; } v; v.f = f;
    unsigned r = v.u + 0x7FFF + ((v.u >> 16) & 1);   // RNE
    return (short)(r >> 16);
}

__device__ __forceinline__ void gll16(const short* g, short* l) {
    __builtin_amdgcn_global_load_lds(
        (const __attribute__((address_space(1))) void*)g,
        (__attribute__((address_space(3))) void*)l, 16, 0, 0);
}

// sizes
#define NE 4
#define CC 384
#define CO 1152
#define TT 8
#define NN 197
#define NPAD 224
#define NB 32
#define BT 256
#define MOEW_ELEMS 5308416   // 4*1152*384*3
#define W_ELEMS    442368    // 1152*384

// ---------------------------------------------------------------
// P0: prep — rf, Y (cls windows, bf16), convert moe_w & weight to bf16
// ---------------------------------------------------------------
__global__ __launch_bounds__(256) void prep_kernel(
    const float* __restrict__ x, const float* __restrict__ rf_w,
    const float* __restrict__ rf_b, const float* __restrict__ moe_w,
    const float* __restrict__ weight,
    short* __restrict__ moeWb, short* __restrict__ Wb,
    short* __restrict__ Yb, float* __restrict__ rf)
{
    int blk = blockIdx.x, tid = threadIdx.x;
    if (blk < NB) {
        __shared__ float clsL[TT * CC];    // [t][c]
        __shared__ float pooled[CC];
        int b = blk;
        for (int flat = tid; flat < TT * CC; flat += 256) {
            int t = flat / CC, c = flat - t * CC;
            clsL[flat] = x[(size_t)(b * TT + t) * NN * CC + c];  // n = 0 (cls token)
        }
        __syncthreads();
        for (int c = tid; c < CC; c += 256) {
            float s = 0.f;
            #pragma unroll
            for (int t = 0; t < TT; t++) s += clsL[t * CC + c];
            pooled[c] = s * 0.125f;
        }
        for (int t = 0; t < TT; t++)
            for (int flat = tid; flat < CC * 3; flat += 256) {
                int c = flat / 3, k = flat - c * 3;
                int u = t + k - 1;
                float v = (u >= 0 && u < TT) ? clsL[u * CC + c] : 0.f;
                Yb[(size_t)(b * TT + t) * (CC * 3) + flat] = f2bf(v);
            }
        __syncthreads();
        int wave = tid >> 6, lane = tid & 63;
        float p = 0.f;
        for (int c = lane; c < CC; c += 64) p += pooled[c] * rf_w[wave * CC + c];
        #pragma unroll
        for (int off = 32; off; off >>= 1) p += __shfl_down(p, off, 64);
        if (lane == 0) rf[b * NE + wave] = p + rf_b[wave];
    } else {
        const long NU = (MOEW_ELEMS + W_ELEMS) / 4;   // float4 units
        long step = (long)(gridDim.x - NB) * 256;
        for (long unit = (long)(blk - NB) * 256 + tid; unit < NU; unit += step) {
            long idx = unit * 4;
            float4 v; short* dst;
            if (idx < MOEW_ELEMS) { v = *(const float4*)(moe_w + idx); dst = moeWb + idx; }
            else { long j = idx - MOEW_ELEMS; v = *(const float4*)(weight + j); dst = Wb + j; }
            short4v s;
            s.x = f2bf(v.x); s.y = f2bf(v.y); s.z = f2bf(v.z); s.w = f2bf(v.w);
            *(short4v*)dst = s;
        }
    }
}

// ---------------------------------------------------------------
// P1: P[4608][256] = moeWb[4608][1152] @ Yb[256][1152]^T   (bf16 MFMA)
// ---------------------------------------------------------------
__global__ __launch_bounds__(256) void gemm_P(
    const short* __restrict__ A, const short* __restrict__ B, float* __restrict__ P)
{
    __shared__ short A_lds[64 * 64];
    __shared__ short B_lds[64 * 64];
    int bm = blockIdx.x, bn = blockIdx.y, tid = threadIdx.x;
    int wave = tid >> 6, lane = tid & 63, l15 = lane & 15, lq = lane >> 4;
    f32x4 acc[4];
    #pragma unroll
    for (int j = 0; j < 4; j++) acc[j] = (f32x4){0.f, 0.f, 0.f, 0.f};

    for (int kk = 0; kk < 1152 / 64; kk++) {
        __syncthreads();
        #pragma unroll
        for (int j2 = 0; j2 < 2; j2++) {
            int flat = j2 * 256 + tid;
            int row = flat >> 3, seg = flat & 7;
            gll16(A + (size_t)(bm * 64 + row) * 1152 + kk * 64 + seg * 8, &A_lds[flat * 8]);
            gll16(B + (size_t)(bn * 64 + row) * 1152 + kk * 64 + seg * 8, &B_lds[flat * 8]);
        }
        __syncthreads();
        #pragma unroll
        for (int ks = 0; ks < 2; ks++) {
            short8 a = *(short8*)&A_lds[(wave * 16 + l15) * 64 + ks * 32 + lq * 8];
            #pragma unroll
            for (int j = 0; j < 4; j++) {
                short8 bfr = *(short8*)&B_lds[(j * 16 + l15) * 64 + ks * 32 + lq * 8];
                acc[j] = __builtin_amdgcn_mfma_f32_16x16x32_bf16(a, bfr, acc[j], 0, 0, 0);
            }
        }
    }
    #pragma unroll
    for (int j = 0; j < 4; j++)
        #pragma unroll
        for (int reg = 0; reg < 4; reg++) {
            int row = bm * 64 + wave * 16 + lq * 4 + reg;   // eo
            int col = bn * 64 + j * 16 + l15;               // bt
            P[(size_t)row * 256 + col] = acc[j][reg];
        }
}

// ---------------------------------------------------------------
// P2: r_ws[bt][o] = 1 + sum_e rf[b][e]*(P[e*1152+o][bt] + moe_b[e][o])
// ---------------------------------------------------------------
__global__ __launch_bounds__(256) void combine_kernel(
    const float* __restrict__ P, const float* __restrict__ rf,
    const float* __restrict__ moe_b, float* __restrict__ r_ws)
{
    __shared__ float rf_l[NB * NE];
    int o = blockIdx.x, tid = threadIdx.x;
    if (tid < NB * NE) rf_l[tid] = rf[tid];
    __syncthreads();
    int b = tid >> 3;
    float acc = 1.0f;
    #pragma unroll
    for (int e = 0; e < NE; e++)
        acc += rf_l[b * NE + e] * (P[(size_t)(e * CO + o) * 256 + tid] + moe_b[e * CO + o]);
    r_ws[(size_t)tid * CO + o] = acc;
}

// ---------------------------------------------------------------
// P3: xs[bt][br][n][c] = bf16( x[bt][n][c] * r_ws[bt][br*384+c] ), n<197; 0 in pad
// grid (256, 14), block 256. Pure BW kernel.
// ---------------------------------------------------------------
__global__ __launch_bounds__(256) void xs_scale(
    const float* __restrict__ x, const float* __restrict__ r_ws,
    short* __restrict__ xs)
{
    __shared__ float r_l[CO];
    int bt = blockIdx.x, ng = blockIdx.y, tid = threadIdx.x;
    for (int i = tid; i < CO; i += 256) r_l[i] = r_ws[(size_t)bt * CO + i];
    __syncthreads();
    #pragma unroll
    for (int it = 0; it < 6; it++) {
        int idx = it * 256 + tid;          // 16 rows x 96 float4
        int row = idx / 96, cu = idx - row * 96;
        int n = ng * 16 + row;
        float4 v = {0.f, 0.f, 0.f, 0.f};
        if (n < NN) v = *(const float4*)(x + ((size_t)bt * NN + n) * CC + cu * 4);
        #pragma unroll
        for (int br = 0; br < 3; br++) {
            const float* rp = &r_l[br * CC + cu * 4];
            short4v s;
            s.x = f2bf(v.x * rp[0]);
            s.y = f2bf(v.y * rp[1]);
            s.z = f2bf(v.z * rp[2]);
            s.w = f2bf(v.w * rp[3]);
            *(short4v*)(xs + ((size_t)(bt * 3 + br) * NPAD + n) * CC + cu * 4) = s;
        }
    }
}

// ---------------------------------------------------------------
// Main: pure bf16 GEMM per (mt, bt, nt): out[bt][o][n] = sum_c W[o][c]*xs[bt][br][n][c]
//       + bias[o]*r_ws[bt][o]
// BM=128 BN=112 BK=64, both sides via global_load_lds, XOR-swizzled LDS.
// ---------------------------------------------------------------
__global__ __launch_bounds__(256) void main_gemm(
    const short* __restrict__ xs, const short* __restrict__ Wb,
    const float* __restrict__ r_ws, const float* __restrict__ bias,
    float* __restrict__ out)
{
    __shared__ short A_lds[128 * 64];   // 16 KB
    __shared__ short B_lds[112 * 64];   // 14 KB

    int g = blockIdx.x;
    int u = g & 7, w2 = g >> 3;
    int mt = w2 % 9;
    int pq = u + 8 * (w2 / 9);    // [0,512)
    int bt = pq >> 1, nt = pq & 1;
    int tid = threadIdx.x;
    int br = mt / 3;

    const short* Abase = Wb + (size_t)(mt * 128) * CC;
    const short* Bbase = xs + ((size_t)(bt * 3 + br) * NPAD + nt * 112) * CC;

    f32x4 acc[2][7];
    #pragma unroll
    for (int i = 0; i < 2; i++)
        #pragma unroll
        for (int j = 0; j < 7; j++) acc[i][j] = (f32x4){0.f, 0.f, 0.f, 0.f};

    int wave = tid >> 6, lane = tid & 63, l15 = lane & 15, lq = lane >> 4;
    int l7 = l15 & 7;

    for (int kk = 0; kk < CC / 64; kk++) {
        __syncthreads();
        // A: 128x64 bf16 = 16KB (1024 chunks), xor-swizzled source mapping
        #pragma unroll
        for (int j2 = 0; j2 < 4; j2++) {
            int flat = j2 * 256 + tid;
            int row = flat >> 3, ss = flat & 7;
            int seg = ss ^ (row & 7);
            gll16(Abase + (size_t)row * CC + kk * 64 + seg * 8, &A_lds[flat * 8]);
        }
        // B: 112x64 bf16 = 14KB (896 chunks)
        #pragma unroll
        for (int j2 = 0; j2 < 4; j2++) {
            int flat = j2 * 256 + tid;
            if (flat < 896) {
                int row = flat >> 3, ss = flat & 7;
                int seg = ss ^ (row & 7);
                gll16(Bbase + (size_t)row * CC + kk * 64 + seg * 8, &B_lds[flat * 8]);
            }
        }
        __syncthreads();
        #pragma unroll
        for (int ks = 0; ks < 2; ks++) {
            int sx = (ks * 4 + lq) ^ l7;    // swizzled segment for this lane
            short8 a0 = *(short8*)&A_lds[(wave * 32      + l15) * 64 + sx * 8];
            short8 a1 = *(short8*)&A_lds[(wave * 32 + 16 + l15) * 64 + sx * 8];
            #pragma unroll
            for (int j = 0; j < 7; j++) {
                short8 bfr = *(short8*)&B_lds[(j * 16 + l15) * 64 + sx * 8];
                acc[0][j] = __builtin_amdgcn_mfma_f32_16x16x32_bf16(a0, bfr, acc[0][j], 0, 0, 0);
                acc[1][j] = __builtin_amdgcn_mfma_f32_16x16x32_bf16(a1, bfr, acc[1][j], 0, 0, 0);
            }
        }
    }

    size_t outbase = (size_t)bt * (CO * NN);
    #pragma unroll
    for (int mi = 0; mi < 2; mi++)
        #pragma unroll
        for (int reg = 0; reg < 4; reg++) {
            int o = mt * 128 + wave * 32 + mi * 16 + lq * 4 + reg;
            float bo = bias[o] * r_ws[(size_t)bt * CO + o];
            #pragma unroll
            for (int j = 0; j < 7; j++) {
                int n = nt * 112 + j * 16 + l15;
                if (n < NN) out[outbase + (size_t)o * NN + n] = acc[mi][j][reg] + bo;
            }
        }
}

// ---------------------------------------------------------------
extern "C" void kernel_launch(void* const* d_in, const int* in_sizes, int n_in,
                              void* d_out, int out_size, void* d_ws, size_t ws_size,
                              hipStream_t stream) {
    const float* x      = (const float*)d_in[0];
    const float* rf_w   = (const float*)d_in[1];
    const float* rf_b   = (const float*)d_in[2];
    const float* moe_w  = (const float*)d_in[3];
    const float* moe_b  = (const float*)d_in[4];
    const float* weight = (const float*)d_in[5];
    const float* bias   = (const float*)d_in[6];
    float* out = (float*)d_out;

    char* ws = (char*)d_ws;
    short* Wb    = (short*)(ws + 0);            //    884,736 B
    short* moeWb = (short*)(ws + 884736);       // 10,616,832 B
    short* Yb    = (short*)(ws + 11501568);     //    589,824 B
    float* rf    = (float*)(ws + 12091392);     //        512 B
    float* P     = (float*)(ws + 12091904);     //  4,718,592 B
    float* r_ws  = (float*)(ws + 16810496);     //  1,179,648 B
    short* xs    = (short*)(ws + 17990144);     // 132,120,576 B -> total ~150 MB

    prep_kernel<<<512, 256, 0, stream>>>(x, rf_w, rf_b, moe_w, weight, moeWb, Wb, Yb, rf);
    gemm_P<<<dim3(72, 4), 256, 0, stream>>>(moeWb, Yb, P);
    combine_kernel<<<1152, 256, 0, stream>>>(P, rf, moe_b, r_ws);
    xs_scale<<<dim3(256, 14), 256, 0, stream>>>(x, r_ws, xs);
    main_gemm<<<4608, 256, 0, stream>>>(xs, Wb, r_ws, bias, out);
}